// Round 11
// baseline (5292.777 us; speedup 1.0000x reference)
//
#include <hip/hip_runtime.h>
#include <hip/hip_bf16.h>

#define H     768
#define G3    2304
#define BATCH 16
#define TLEN  1024
#define DOUT  512
#define SLICE 32
#define WPG   24      // workgroups per scan group (768/32)
#define NWG   256     // launched; coordinator selects 160 workers, 96 exit
#define NTHR  384     // 6 waves
#define TMO   4096    // poll iterations before sticky agent fallback

typedef __attribute__((ext_vector_type(8))) short short8;
typedef __attribute__((ext_vector_type(4))) float f32x4;
typedef __attribute__((ext_vector_type(4))) unsigned int u32x4;

union U8 { short8 s; unsigned u[4]; unsigned long long q[2]; };

__device__ __forceinline__ float b2f(ushort u) {
  union { unsigned int ui; float f; } v; v.ui = ((unsigned int)u) << 16; return v.f;
}
__device__ __forceinline__ ushort f2b(float f) {
  union { float f; unsigned int ui; } v; v.f = f;
  unsigned int u = v.ui;
  return (ushort)((u + 0x7fffu + ((u >> 16) & 1u)) >> 16);
}

// ---- agent-scope (cross-XCD coherent, LLC) accessors ----
__device__ __forceinline__ unsigned long long agent_ld64(const void* p) {
  return __hip_atomic_load((const unsigned long long*)p, __ATOMIC_RELAXED, __HIP_MEMORY_SCOPE_AGENT);
}
__device__ __forceinline__ unsigned agent_ld32(const void* p) {
  return __hip_atomic_load((const unsigned*)p, __ATOMIC_RELAXED, __HIP_MEMORY_SCOPE_AGENT);
}
__device__ __forceinline__ void agent_st32(void* p, unsigned v) {
  __hip_atomic_store((unsigned*)p, v, __ATOMIC_RELAXED, __HIP_MEMORY_SCOPE_AGENT);
}
__device__ __forceinline__ void agent_st64(void* p, unsigned long long v) {
  __hip_atomic_store((unsigned long long*)p, v, __ATOMIC_RELAXED, __HIP_MEMORY_SCOPE_AGENT);
}

// ---- intra-XCD (L2) accessors: plain store (write-through to L2) + sc0 load
__device__ __forceinline__ void l2_st32(void* p, unsigned v) {
  __hip_atomic_store((unsigned*)p, v, __ATOMIC_RELAXED, __HIP_MEMORY_SCOPE_WORKGROUP);
}
__device__ __forceinline__ unsigned l2_ld32(const void* p) {
  unsigned v;
  asm volatile("global_load_dword %0, %1, off sc0\n\ts_waitcnt vmcnt(0)"
               : "=v"(v) : "v"(p) : "memory");
  return v;
}

// 64B loads: agent (sc0 sc1, LLC) and intra-XCD (sc0, own-XCD L2).
__device__ __forceinline__ void ld64B_agent(const void* p, u32x4* r) {
  asm volatile(
    "global_load_dwordx4 %0, %4, off sc0 sc1\n\t"
    "global_load_dwordx4 %1, %4, off offset:16 sc0 sc1\n\t"
    "global_load_dwordx4 %2, %4, off offset:32 sc0 sc1\n\t"
    "global_load_dwordx4 %3, %4, off offset:48 sc0 sc1\n\t"
    "s_waitcnt vmcnt(0)"
    : "=&v"(r[0]), "=&v"(r[1]), "=&v"(r[2]), "=&v"(r[3])
    : "v"(p) : "memory");
}
__device__ __forceinline__ void ld64B_sc0(const void* p, u32x4* r) {
  asm volatile(
    "global_load_dwordx4 %0, %4, off sc0\n\t"
    "global_load_dwordx4 %1, %4, off offset:16 sc0\n\t"
    "global_load_dwordx4 %2, %4, off offset:32 sc0\n\t"
    "global_load_dwordx4 %3, %4, off offset:48 sc0\n\t"
    "s_waitcnt vmcnt(0)"
    : "=&v"(r[0]), "=&v"(r[1]), "=&v"(r[2]), "=&v"(r[3])
    : "v"(p) : "memory");
}

// 16-byte-granular load of 8 elements as bf16 fragment (plain/cached path).
__device__ __forceinline__ short8 loadA8(const void* base, bool bf, size_t eidx) {
  if (bf) return *(const short8*)((const ushort*)base + eidx);
  const uint4* f = (const uint4*)((const float*)base + eidx);
  uint4 lo = f[0];
  uint4 hi = f[1];
  U8 r;
  r.u[0] = __builtin_amdgcn_perm(lo.y, lo.x, 0x07060302);
  r.u[1] = __builtin_amdgcn_perm(lo.w, lo.z, 0x07060302);
  r.u[2] = __builtin_amdgcn_perm(hi.y, hi.x, 0x07060302);
  r.u[3] = __builtin_amdgcn_perm(hi.w, hi.z, 0x07060302);
  return r.s;
}
__device__ __forceinline__ short8 loadW8(const void* base, bool bf, size_t eidx) {
  if (bf) return *(const short8*)((const ushort*)base + eidx);
  const float* f = (const float*)base + eidx;
  short8 r;
  #pragma unroll
  for (int i = 0; i < 8; i++) r[i] = (short)f2b(f[i]);
  return r;
}
__device__ __forceinline__ float loadS(const void* p, bool bf, size_t i) {
  return bf ? b2f(((const ushort*)p)[i]) : ((const float*)p)[i];
}

__device__ __forceinline__ bool detect_bf16(const unsigned* xw, int tid, int nthr, int* sh) {
  if (tid == 0) *sh = 0;
  __syncthreads();
  int c = 0;
  for (int i = tid; i < 4096; i += nthr) {
    int e = (int)((xw[i] >> 7) & 0xFF);
    c += (e >= 110 && e <= 140) ? 1 : 0;
  }
  atomicAdd(sh, c);
  __syncthreads();
  return *sh > 2048;
}

// flag line: flags[((grp*WPG + wgi)*4 + rep)*32], 128B apart
__device__ __forceinline__ unsigned* flagp(unsigned* flags, int grp, int wgi, int rep) {
  return flags + (((grp * WPG + wgi) * 4 + rep) * 32);
}

// ---------------------------------------------------------------------------
// R8 (verified) + XCD-clustered recurrent groups, fully fallback-safe.
// Roles assigned at runtime: 256 WGs publish XCC_ID (numeric s_getreg
// encoding, builtin); WG0 places L1 on the argmax XCD (pigeonhole: >=32
// WGs there) and GH2 on the next argmax; GX1/GX2/FC from the remainder;
// 96 surplus WGs exit.  Protocol (lags {0,1,2,4}, wait sets, replicas,
// 4-deep slots) is IDENTICAL to R8.  Transport deltas only:
//   - L1/GH2 keep a LOCAL history (h1L / y2L, plain stores -> own-XCD L2)
//     next to the R8 agent stores (h1buf / y2, unchanged, for GX2/FC).
//   - r0 flag (peers-only line) goes via L2: combine threads drain their
//     L2 store (cheap vmcnt(0); agent store issued AFTER), last combine
//     wave posts r0 plain.  r1/r2/r3 post after the barrier (agent), R8.
//   - Peers poll r0 with sc0 loads and stage from the local history with
//     sc0 64B loads.  STICKY TIMEOUT FALLBACK: if r0 doesn't arrive in
//     TMO polls (wrong XCC read / non-coherent placement), the consumer
//     permanently switches to r1(agent)+agent data = exact R8 path.
//     Wrong XCD info therefore degrades to R8 performance, never hangs.
// FC group identical to R8 (reads y2 via agent, GH2 r2/r3 flags).
// ---------------------------------------------------------------------------
__global__ __launch_bounds__(NTHR) void scan_kernel(
    const void* __restrict__ x,        // [16][1024][768]
    const void* __restrict__ w_ih,     // [2][2304][768]
    const void* __restrict__ w_hh,     // [2][2304][768]
    const void* __restrict__ b_ih,     // [2][2304]
    const void* __restrict__ b_hh,     // [2][2304]
    const void* __restrict__ w_fc,     // [512][768]
    const void* __restrict__ b_fc,     // [512]
    unsigned int* flags,               // [4][24][4][32] padded flags (zeroed)
    unsigned int* reg,                 // [256] xcd publish (zeroed)
    unsigned int* asg,                 // [256] role assignment (zeroed)
    ushort* h1buf,                     // [4][16][768] bf16 (agent, for GX2)
    ushort* h1L,                       // [4][16][768] bf16 (L2-local)
    ushort* y2L,                       // [4][16][768] bf16 (L2-local)
    float*  gxbuf1,                    // [4][24][16][96] f32
    float*  gxbuf2,                    // [4][24][16][96] f32
    ushort* y2,                        // [16][1024][768] bf16 (= h2 history)
    void* __restrict__ out)            // [16][1024][512] bf16 or f32
{
  const int tid  = threadIdx.x;
  const int wave = tid >> 6;           // 0..5
  const int lane = tid & 63;
  const int quad = lane >> 4;          // 0..3

  __shared__ ushort h_lds[BATCH * H];      // staged A tile (swizzled), 24 KB
  __shared__ float ghs[96 * 17];           // MFMA C tile [gate-col][batch]
  __shared__ float hold[BATCH * SLICE];    // persistent fp32 h slice
  __shared__ float bih_s[96], bhh_s[96];
  __shared__ unsigned donecnt[2];          // fast-post arrival counters
  __shared__ unsigned cxA[NWG];            // coordinator scratch (WG0)
  __shared__ unsigned caA[NWG];
  __shared__ unsigned masg;                // my assignment broadcast
  __shared__ int fbsh;                     // sticky fallback signal
  __shared__ int detsh;

  const bool isbf = detect_bf16((const unsigned*)x, tid, NTHR, &detsh);

  // ---- publish XCC_ID (numeric hwreg(20,0,4) encoding; garbage-safe) ----
  unsigned xcc = __builtin_amdgcn_s_getreg(20 | (3 << 11)) & 7u;
  if (tid == 0) agent_st32(&reg[blockIdx.x], xcc | 8u);
  if (blockIdx.x == 0) {
    for (int i = tid; i < NWG; i += NTHR) {
      unsigned v;
      while ((v = agent_ld32(&reg[i])) == 0u) __builtin_amdgcn_s_sleep(8);
      cxA[i] = v & 7u;
    }
    __syncthreads();
    if (tid == 0) {
      int cnt[8];
      for (int i = 0; i < 8; i++) cnt[i] = 0;
      for (int i = 0; i < NWG; i++) { caA[i] = 0u; cnt[cxA[i]]++; }
      // L1 on argmax XCD (>= 32 by pigeonhole -> always clustered)
      int xa = 0;
      for (int x2 = 1; x2 < 8; x2++) if (cnt[x2] > cnt[xa]) xa = x2;
      int got = 0;
      for (int i = 0; i < NWG && got < WPG; i++)
        if (!caA[i] && (int)cxA[i] == xa) {
          caA[i] = 1u | (1u << 1) | ((unsigned)got << 4) | 0x400u;
          cnt[xa]--; got++;
        }
      // GH2 on argmax remaining (>= 29 by pigeonhole -> clustered)
      int xb = 0;
      for (int x2 = 1; x2 < 8; x2++) if (cnt[x2] > cnt[xb]) xb = x2;
      const unsigned cl3 = (cnt[xb] >= WPG) ? 0x400u : 0u;
      got = 0;
      for (int i = 0; i < NWG && got < WPG; i++) {
        if (caA[i]) continue;
        if (cl3 && (int)cxA[i] != xb) continue;
        caA[i] = 1u | (3u << 1) | ((unsigned)got << 4) | cl3;
        got++;
      }
      // GX1, GX2, FC from remainder in index order
      const int gcnt[3] = {WPG, WPG, 64};
      const unsigned ggrp[3] = {0u, 2u, 4u};
      for (int k = 0; k < 3; k++) {
        got = 0;
        for (int i = 0; i < NWG && got < gcnt[k]; i++)
          if (!caA[i]) { caA[i] = 1u | (ggrp[k] << 1) | ((unsigned)got << 4); got++; }
      }
      for (int i = 0; i < NWG; i++) if (!caA[i]) caA[i] = 0x8000u;
    }
    __syncthreads();
    for (int i = tid; i < NWG; i += NTHR) agent_st32(&asg[i], caA[i]);
  }
  if (tid == 0) {
    unsigned v;
    while ((v = agent_ld32(&asg[blockIdx.x])) == 0u) __builtin_amdgcn_s_sleep(8);
    masg = v;
  }
  __syncthreads();
  const unsigned a = masg;
  if (a == 0x8000u) return;              // surplus WG, uniform exit
  const int grp  = (int)((a >> 1) & 7u);
  const int wgi  = (int)((a >> 4) & 63u);
  const bool clu = (a & 0x400u) != 0u;
  const bool isL = (grp == 1 || grp == 3);

  // =========================== FC group (R8 verbatim) =====================
  if (grp == 4) {
    const int fcw = wgi;               // 0..63
    const unsigned* fpoll = (wave == 0 && lane < WPG)
        ? flagp(flags, 3, lane, (fcw < 32) ? 2 : 3) : nullptr;
    const int sb  = tid / 24;          // 0..15 (batch row)
    const int seg = tid % 24;          // 0..23 (32-elem segment)
    const int sx  = sb & 7;
    const int ar  = lane & 15;
    const int arx = ar & 7;

    for (int i = 0; i < 16; i++) {
      const int t = fcw + 64 * i;
      if (wave == 0) {
        const int tgt = t + 5;
        for (;;) {
          int v = fpoll ? (int)agent_ld32(fpoll) : 0x7FFFFFFF;
          if (__ballot(v < tgt) == 0ull) break;
          __builtin_amdgcn_s_sleep(8);
        }
      }
      __syncthreads();

      {
        const ushort* src = y2 + ((size_t)sb * TLEN + t) * H + seg * 32;
        u32x4 r4[4];
        ld64B_agent(src, r4);
        #pragma unroll
        for (int j = 0; j < 4; j++)
          *(u32x4*)&h_lds[sb * H + (((seg * 4 + j) ^ sx) * 8)] = r4[j];
      }
      __syncthreads();

      if (wave < 4) {
        const int n0 = wave * 128;
        const ushort* abase = &h_lds[ar * H];
        f32x4 acc[8];
        #pragma unroll
        for (int nt = 0; nt < 8; nt++) acc[nt] = (f32x4){0.f, 0.f, 0.f, 0.f};
        for (int kk = 0; kk < 12; kk++) {
          short8 a0 = *(const short8*)&abase[((quad + 4 * kk) ^ arx) * 8];
          short8 a1 = *(const short8*)&abase[((quad + 4 * (kk + 12)) ^ arx) * 8];
          #pragma unroll
          for (int nt = 0; nt < 8; nt++) {
            const size_t bb = (size_t)(n0 + nt * 16 + ar) * H + quad * 8;
            short8 b0 = loadA8(w_fc, isbf, bb + kk * 32);
            short8 b1 = loadA8(w_fc, isbf, bb + (kk + 12) * 32);
            acc[nt] = __builtin_amdgcn_mfma_f32_16x16x32_bf16(a0, b0, acc[nt], 0, 0, 0);
            acc[nt] = __builtin_amdgcn_mfma_f32_16x16x32_bf16(a1, b1, acc[nt], 0, 0, 0);
          }
        }
        #pragma unroll
        for (int nt = 0; nt < 8; nt++) {
          #pragma unroll
          for (int i2 = 0; i2 < 4; i2++) {
            const int b = quad * 4 + i2;
            const int n = n0 + nt * 16 + ar;
            float v = acc[nt][i2] + loadS(b_fc, isbf, n);
            float g = 0.5f * v * (1.0f + erff(v * 0.70710678118654752f));
            if (isbf) ((ushort*)out)[((size_t)b * TLEN + t) * DOUT + n] = f2b(g);
            else      ((float*)out)[((size_t)b * TLEN + t) * DOUT + n] = g;
          }
        }
      }
      __syncthreads();
    }
    return;
  }

  // =========================== scan groups ================================
  if (tid < 2) donecnt[tid] = 0u;
  if (tid == 0) fbsh = 0;
  for (int i = tid; i < BATCH * SLICE; i += NTHR) hold[i] = 0.0f;

  if (isL) {
    size_t boff = (grp == 3) ? (size_t)G3 : 0;
    for (int gf = tid; gf < 96; gf += NTHR) {
      size_t gidx = boff + (size_t)(gf >> 5) * H + wgi * SLICE + (gf & 31);
      bih_s[gf] = loadS(b_ih, isbf, gidx);
      bhh_s[gf] = loadS(b_hh, isbf, gidx);
    }
  }

  // ---- poll pointers: pollA = primary (L2 for clustered peers-lines),
  //      pollF = agent fallback (same semantics; r1 replica for peers) ----
  const unsigned* pollA = nullptr;
  const unsigned* pollF = nullptr;
  int polloff = 0;
  bool ploc = false;
  if (wave == 0) {
    if (grp == 0) {
      if (lane == 0) { pollA = pollF = flagp(flags, 1, wgi, 2); polloff = -2; }
    } else if (grp == 1) {
      if      (lane == 0)  { pollA = pollF = flagp(flags, 0, wgi, 0); polloff = 0; }
      else if (lane <= 24) { pollA = flagp(flags, 1, lane - 1, 0);
                             pollF = flagp(flags, 1, lane - 1, 1);
                             polloff = 0; ploc = clu; }
      else if (lane <= 48) { pollA = pollF = flagp(flags, 2, lane - 25, 0); polloff = -2; }
    } else if (grp == 2) {
      if      (lane < 24)  { pollA = pollF = flagp(flags, 1, lane, 1); polloff = 0; }
      else if (lane == 24) { pollA = pollF = flagp(flags, 3, wgi, 1);  polloff = -1; }
    } else {
      if      (lane == 0)  { pollA = pollF = flagp(flags, 2, wgi, 1);  polloff = -1; }
      else if (lane <= 24) { pollA = flagp(flags, 3, lane - 1, 0);
                             pollF = flagp(flags, 3, lane - 1, 1);
                             polloff = 0; ploc = clu; }
    }
  }

  // ---- load this wave's B-fragments (16 gate rows x K=768) into registers --
  const void* Wmat = (grp == 0 || grp == 2) ? w_ih : w_hh;
  const size_t woff = (grp >= 2) ? (size_t)G3 * H : 0;
  const int gate   = wave >> 1;                       // 0=r,1=z,2=n
  const int gfbase = gate * SLICE + (wave & 1) * 16;  // within-wg flat gate base
  const int nrow   = gate * H + wgi * SLICE + (wave & 1) * 16 + (lane & 15);
  const size_t wbase = woff + (size_t)nrow * H + quad * 8;

  short8 bfrag[24];
  #pragma unroll
  for (int kk = 0; kk < 24; kk++)
    bfrag[kk] = loadW8(Wmat, isbf, wbase + kk * 32);

  // staging decomposition: thread -> (row b, 32-elem segment = 4 x 16B units)
  const int sb  = tid / 24;            // 0..15
  const int seg = tid % 24;            // 0..23
  const int sx  = sb & 7;              // staging swizzle key

  // combine decomposition: 256 threads, pairs of columns
  const int pb = tid >> 4;             // batch
  const int pj = (tid & 15) * 2;       // column pair
  const bool pact = isL && (tid < BATCH * SLICE / 2);

  const int lag = (grp == 1) ? 1 : ((grp == 2) ? 2 : ((grp == 3) ? 4 : 0));

  bool fb = false;                     // per-thread sticky fallback (wave0)

  __syncthreads();

  for (int t = 0; t < TLEN + 4; t++) {
    const int tau = t - lag;
    const bool active = (tau >= 0) && (tau < TLEN);

    if (active) {
      // ---- dependency wait (timeout -> sticky agent fallback) ----
      if (wave == 0) {
        int iter = 0;
        for (;;) {
          int v = 0x7FFFFFFF;
          if (pollA) v = (ploc && !fb) ? (int)l2_ld32(pollA) : (int)agent_ld32(pollF);
          if (__ballot(v < t + polloff) == 0ull) break;
          if (ploc && !fb && ++iter > TMO) { fb = true; fbsh = 1; }
          __builtin_amdgcn_s_sleep(1);
        }
      }
      __syncthreads();
      const bool useloc = clu && (fbsh == 0);

      // ---- early-issue combine-phase gx loads (producer >=1 tick ahead) --
      unsigned long long gr01 = 0, gz01 = 0, gn01 = 0;
      if (pact) {
        const float* gxr = ((grp == 1) ? gxbuf1 : gxbuf2)
            + ((size_t)((tau & 3) * WPG + wgi) * BATCH + pb) * 96;
        gr01 = agent_ld64(gxr + pj);
        gz01 = agent_ld64(gxr + 32 + pj);
        gn01 = agent_ld64(gxr + 64 + pj);
      }

      // ---- stage A tile (16 x 768) into LDS (XOR-swizzled units) ----
      if (grp == 0) {
        const size_t srcbase = ((size_t)sb * TLEN + tau) * H + seg * 32;
        #pragma unroll
        for (int i = 0; i < 4; i++) {
          short8 v = loadA8(x, isbf, srcbase + i * 8);
          *(short8*)&h_lds[sb * H + (((seg * 4 + i) ^ sx) * 8)] = v;
        }
      } else {
        const int hstep = (grp == 3) ? (t - 5) : (t - 2);
        u32x4 r4[4];
        if (hstep >= 0) {
          if (grp == 2) {
            const ushort* src = h1buf + (size_t)(hstep & 3) * (BATCH * H)
                                      + (size_t)sb * H + seg * 32;
            ld64B_agent(src, r4);
          } else if (grp == 1) {
            const ushort* src = (useloc ? h1L : h1buf)
                + (size_t)(hstep & 3) * (BATCH * H) + (size_t)sb * H + seg * 32;
            if (useloc) ld64B_sc0(src, r4); else ld64B_agent(src, r4);
          } else {
            if (useloc) {
              const ushort* src = y2L + (size_t)(hstep & 3) * (BATCH * H)
                                      + (size_t)sb * H + seg * 32;
              ld64B_sc0(src, r4);
            } else {
              const ushort* src = y2 + ((size_t)sb * TLEN + hstep) * H + seg * 32;
              ld64B_agent(src, r4);
            }
          }
        } else {
          r4[0] = (u32x4){0u, 0u, 0u, 0u};
          r4[1] = r4[0]; r4[2] = r4[0]; r4[3] = r4[0];
        }
        #pragma unroll
        for (int j = 0; j < 4; j++)
          *(u32x4*)&h_lds[sb * H + (((seg * 4 + j) ^ sx) * 8)] = r4[j];
      }
      __syncthreads();

      // ---- MFMA: A from LDS (swizzled read), B from registers ----
      const int ar  = lane & 15;
      const int arx = ar & 7;
      const ushort* abase = &h_lds[ar * H];
      f32x4 acc0 = {0.f, 0.f, 0.f, 0.f}, acc1 = {0.f, 0.f, 0.f, 0.f};
      #pragma unroll
      for (int kk = 0; kk < 12; kk++) {
        short8 a0 = *(const short8*)&abase[((quad + 4 * kk) ^ arx) * 8];
        short8 a1 = *(const short8*)&abase[((quad + 4 * (kk + 12)) ^ arx) * 8];
        acc0 = __builtin_amdgcn_mfma_f32_16x16x32_bf16(a0, bfrag[kk],      acc0, 0, 0, 0);
        acc1 = __builtin_amdgcn_mfma_f32_16x16x32_bf16(a1, bfrag[kk + 12], acc1, 0, 0, 0);
      }
      f32x4 acc = acc0 + acc1;

      // ---- stage C tile to LDS ----
      #pragma unroll
      for (int i = 0; i < 4; i++)
        ghs[(gfbase + ar) * 17 + quad * 4 + i] = acc[i];
      __syncthreads();

      if (!isL) {
        // pack gx slice [16][96] f32 -> coalesced 8B agent stores
        float* gxout = ((grp == 0) ? gxbuf1 : gxbuf2)
            + ((size_t)(tau & 3) * WPG + wgi) * BATCH * 96;
        const int m  = tid / 24;
        const int c4 = (tid % 24) * 4;
        union { unsigned long long q; float f[2]; } p0, p1;
        p0.f[0] = ghs[(c4 + 0) * 17 + m];
        p0.f[1] = ghs[(c4 + 1) * 17 + m];
        p1.f[0] = ghs[(c4 + 2) * 17 + m];
        p1.f[1] = ghs[(c4 + 3) * 17 + m];
        agent_st64(gxout + (size_t)m * 96 + c4,     p0.q);
        agent_st64(gxout + (size_t)m * 96 + c4 + 2, p1.q);
      } else if (pact) {
        union { unsigned long long q; float f[2]; } ur, uz, un;
        ur.q = gr01; uz.q = gz01; un.q = gn01;
        unsigned hpack = 0;
        #pragma unroll
        for (int s = 0; s < 2; s++) {
          const int j = pj + s;
          float rpre = ur.f[s] + bih_s[j]      + ghs[j * 17 + pb]        + bhh_s[j];
          float zpre = uz.f[s] + bih_s[32 + j] + ghs[(32 + j) * 17 + pb] + bhh_s[32 + j];
          float hn   = ghs[(64 + j) * 17 + pb] + bhh_s[64 + j];
          float r = 1.0f / (1.0f + expf(-rpre));
          float z = 1.0f / (1.0f + expf(-zpre));
          float n = tanhf(un.f[s] + bih_s[64 + j] + r * hn);
          float hnew = (1.0f - z) * n + z * hold[pb * SLICE + j];
          hold[pb * SLICE + j] = hnew;
          hpack |= ((unsigned)f2b(hnew)) << (16 * s);
        }
        const size_t soff = (size_t)(tau & 3) * (BATCH * H)
                          + (size_t)pb * H + wgi * SLICE + pj;
        if (clu) {
          // L2-local store + cheap drain + fast-post r0 (L2)
          l2_st32(((grp == 1) ? h1L : y2L) + soff, hpack);
          asm volatile("s_waitcnt vmcnt(0)" ::: "memory");
          if ((tid & 63) == 0) {
            unsigned prev = atomicAdd(&donecnt[t & 1], 1u);
            if (prev == 3u) {
              donecnt[t & 1] = 0u;
              l2_st32(flagp(flags, grp, wgi, 0), (unsigned)(t + 1));
            }
          }
        }
        // agent copy (cross-XCD consumers; drains at end-of-tick barrier)
        if (grp == 1)
          agent_st32(h1buf + soff, hpack);
        else
          agent_st32(&y2[((size_t)pb * TLEN + tau) * H + wgi * SLICE + pj], hpack);
      }
    }

    // ---- end-of-tick barrier + flag posts (r0 unless fast-posted) ----
    __syncthreads();                       // drains vmcnt: agent stores visible
    if (tid >= 1 && tid < 4)
      agent_st32(flagp(flags, grp, wgi, tid), (unsigned)(t + 1));
    if (tid == 0 && !(isL && active && clu)) {
      if (isL && clu) l2_st32(flagp(flags, grp, wgi, 0), (unsigned)(t + 1));
      else            agent_st32(flagp(flags, grp, wgi, 0), (unsigned)(t + 1));
    }
  }
}

extern "C" void kernel_launch(void* const* d_in, const int* in_sizes, int n_in,
                              void* d_out, int out_size, void* d_ws, size_t ws_size,
                              hipStream_t stream) {
  const void* x    = d_in[0];
  const void* w_ih = d_in[1];
  const void* w_hh = d_in[2];
  const void* b_ih = d_in[3];
  const void* b_hh = d_in[4];
  const void* w_fc = d_in[5];
  const void* b_fc = d_in[6];

  char* ws = (char*)d_ws;
  // layout: [0,49152) flags[4][24][4][32] | [49152,50176) reg[256] |
  //         [50176,51200) asg[256] | [53248,151552) h1buf (4-deep) |
  //         [151552,741376) gx1 | [741376,1331200) gx2 |
  //         [1331200,1429504) h1L | [1429504,1527808) y2L |
  //         [1527808,26693632) y2 (= h2 history)
  unsigned int* flags = (unsigned int*)(ws);
  unsigned int* reg   = (unsigned int*)(ws + 49152);
  unsigned int* asg   = (unsigned int*)(ws + 50176);
  ushort* h1buf  = (ushort*)(ws + 53248);
  float*  gxbuf1 = (float*)(ws + 151552);
  float*  gxbuf2 = (float*)(ws + 741376);
  ushort* h1L    = (ushort*)(ws + 1331200);
  ushort* y2L    = (ushort*)(ws + 1429504);
  ushort* y2     = (ushort*)(ws + 1527808);

  hipMemsetAsync(ws, 0, 51200, stream);  // flags + reg + asg (data flag-gated)
  scan_kernel<<<dim3(NWG), dim3(NTHR), 0, stream>>>(
      x, w_ih, w_hh, b_ih, b_hh, w_fc, b_fc, flags, reg, asg,
      h1buf, h1L, y2L, gxbuf1, gxbuf2, y2, d_out);
}

// Round 12
// 3598.957 us; speedup vs baseline: 1.4706x; 1.4706x over previous
//
#include <hip/hip_runtime.h>
#include <hip/hip_bf16.h>

#define H     768
#define G3    2304
#define BATCH 16
#define TLEN  1024
#define DOUT  512
#define SLICE 32
#define WPG   24      // workgroups per scan group (768/32)
#define NSCAN 96      // 4 scan groups * 24
#define NFC   64      // fused fc workgroups
#define NWG   160     // 96 scan + 64 fc
#define NTHR  384     // 6 waves

typedef __attribute__((ext_vector_type(8))) short short8;
typedef __attribute__((ext_vector_type(4))) float f32x4;
typedef __attribute__((ext_vector_type(4))) unsigned int u32x4;

union U8 { short8 s; unsigned u[4]; unsigned long long q[2]; };

__device__ __forceinline__ float b2f(ushort u) {
  union { unsigned int ui; float f; } v; v.ui = ((unsigned int)u) << 16; return v.f;
}
__device__ __forceinline__ ushort f2b(float f) {
  union { float f; unsigned int ui; } v; v.f = f;
  unsigned int u = v.ui;
  return (ushort)((u + 0x7fffu + ((u >> 16) & 1u)) >> 16);
}

// ---- agent-scope (cross-XCD coherent) relaxed accessors ----
__device__ __forceinline__ unsigned long long agent_ld64(const void* p) {
  return __hip_atomic_load((const unsigned long long*)p, __ATOMIC_RELAXED, __HIP_MEMORY_SCOPE_AGENT);
}
__device__ __forceinline__ unsigned agent_ld32(const void* p) {
  return __hip_atomic_load((const unsigned*)p, __ATOMIC_RELAXED, __HIP_MEMORY_SCOPE_AGENT);
}
__device__ __forceinline__ void agent_st32(void* p, unsigned v) {
  __hip_atomic_store((unsigned*)p, v, __ATOMIC_RELAXED, __HIP_MEMORY_SCOPE_AGENT);
}
__device__ __forceinline__ void agent_st64(void* p, unsigned long long v) {
  __hip_atomic_store((unsigned long long*)p, v, __ATOMIC_RELAXED, __HIP_MEMORY_SCOPE_AGENT);
}

// 64B coherent (agent-scope, cache-bypassing) load: 4 x dwordx4 with sc0 sc1.
__device__ __forceinline__ void ld64B_agent(const void* p, u32x4* r) {
  asm volatile(
    "global_load_dwordx4 %0, %4, off sc0 sc1\n\t"
    "global_load_dwordx4 %1, %4, off offset:16 sc0 sc1\n\t"
    "global_load_dwordx4 %2, %4, off offset:32 sc0 sc1\n\t"
    "global_load_dwordx4 %3, %4, off offset:48 sc0 sc1\n\t"
    "s_waitcnt vmcnt(0)"
    : "=&v"(r[0]), "=&v"(r[1]), "=&v"(r[2]), "=&v"(r[3])
    : "v"(p) : "memory");
}

// 16-byte-granular load of 8 elements as bf16 fragment (plain/cached path).
__device__ __forceinline__ short8 loadA8(const void* base, bool bf, size_t eidx) {
  if (bf) return *(const short8*)((const ushort*)base + eidx);
  const uint4* f = (const uint4*)((const float*)base + eidx);
  uint4 lo = f[0];
  uint4 hi = f[1];
  U8 r;
  r.u[0] = __builtin_amdgcn_perm(lo.y, lo.x, 0x07060302);
  r.u[1] = __builtin_amdgcn_perm(lo.w, lo.z, 0x07060302);
  r.u[2] = __builtin_amdgcn_perm(hi.y, hi.x, 0x07060302);
  r.u[3] = __builtin_amdgcn_perm(hi.w, hi.z, 0x07060302);
  return r.s;
}
__device__ __forceinline__ short8 loadW8(const void* base, bool bf, size_t eidx) {
  if (bf) return *(const short8*)((const ushort*)base + eidx);
  const float* f = (const float*)base + eidx;
  short8 r;
  #pragma unroll
  for (int i = 0; i < 8; i++) r[i] = (short)f2b(f[i]);
  return r;
}
__device__ __forceinline__ float loadS(const void* p, bool bf, size_t i) {
  return bf ? b2f(((const ushort*)p)[i]) : ((const float*)p)[i];
}

__device__ __forceinline__ bool detect_bf16(const unsigned* xw, int tid, int nthr, int* sh) {
  if (tid == 0) *sh = 0;
  __syncthreads();
  int c = 0;
  for (int i = tid; i < 4096; i += nthr) {
    int e = (int)((xw[i] >> 7) & 0xFF);
    c += (e >= 110 && e <= 140) ? 1 : 0;
  }
  atomicAdd(sh, c);
  __syncthreads();
  return *sh > 2048;
}

// flag line: flags[((grp*WPG + wgi)*4 + rep)*32], 128B apart
__device__ __forceinline__ unsigned* flagp(unsigned* flags, int grp, int wgi, int rep) {
  return flags + (((grp * WPG + wgi) * 4 + rep) * 32);
}

// ---------------------------------------------------------------------------
// Persistent pipelined GRU scan (R8, verified) with 8-DEEP SLACK BUFFERS.
// Scan groups: 0=GX1 (w_ih1 @ x[s]),  1=L1 (w_hh1 @ h1 + combine -> h1[s]),
//              2=GX2 (w_ih2 @ h1[s]), 3=GH2 (w_hh2 @ h2 + combine -> y2[s])
// lag = {0,1,2,4}; tau = t - lag. gx1/gx2/h1 8-deep (slot = step & 7);
// y2 = full h2 history. Flag value = ticks completed (posted t+1 after the
// end-of-tick drain barrier). Waits (flag >= t + off), offsets re-derived
// for 8-deep slot reuse (overwriter of slot s waits for the reader of the
// previous occupant, 8 steps back):
//   GX1: F_L1 r2[wgi]  -6   (gx1[t] overwrites gx1[t-8], read by L1 @ t-7)
//   L1 : F_GX1 r0[wgi]  0   (gx1[t-1] data-ready; pre-satisfied)
//        F_L1  r0[all]  0   (peers' h1[t-2])               <- critical
//        F_GX2 r0[all] -6   (h1[t-1] overwrites h1[t-9], read by GX2 @ t-7)
//   GX2: F_L1  r1[all]  0   (h1[t-2] data-ready)
//        F_GH2 r1[wgi] -5   (gx2[t-2] overwrites gx2[t-10], read @ t-6)
//   GH2: F_GX2 r1[wgi] -1   (gx2[t-4] data-ready, stored @ GX2 tick t-2)
//        F_GH2 r0[all]  0   (peers' h2[t-5] in y2)         <- critical
// Deeper slack means the non-critical edges can never become momentarily
// binding under per-tick jitter; the critical cycles are untouched.
// FC group (wg 96..159): WG fcw owns t = fcw + 64*i (i=0..15); waits all 24
// GH2 flags >= t+5 (replicas r2/r3), stages y2[:,t,:], MFMA vs w_fc,
// bias + exact GELU -> out.  Purely additive; no back-pressure.
// ---------------------------------------------------------------------------
__global__ __launch_bounds__(NTHR) void scan_kernel(
    const void* __restrict__ x,        // [16][1024][768]
    const void* __restrict__ w_ih,     // [2][2304][768]
    const void* __restrict__ w_hh,     // [2][2304][768]
    const void* __restrict__ b_ih,     // [2][2304]
    const void* __restrict__ b_hh,     // [2][2304]
    const void* __restrict__ w_fc,     // [512][768]
    const void* __restrict__ b_fc,     // [512]
    unsigned int* flags,               // [4][24][4][32] padded flags (zeroed)
    ushort* h1buf,                     // [8][16][768] bf16
    float*  gxbuf1,                    // [8][24][16][96] f32 (per-WG slices)
    float*  gxbuf2,                    // [8][24][16][96] f32
    ushort* y2,                        // [16][1024][768] bf16 (= h2 history)
    void* __restrict__ out)            // [16][1024][512] bf16 or f32
{
  const int wg   = blockIdx.x;
  const int tid  = threadIdx.x;
  const int wave = tid >> 6;           // 0..5
  const int lane = tid & 63;
  const int quad = lane >> 4;          // 0..3

  __shared__ ushort h_lds[BATCH * H];      // staged A tile (swizzled), 24 KB
  __shared__ float ghs[96 * 17];           // MFMA C tile [gate-col][batch]
  __shared__ float hold[BATCH * SLICE];    // persistent fp32 h slice
  __shared__ float bih_s[96], bhh_s[96];
  __shared__ int   detsh;

  const bool isbf = detect_bf16((const unsigned*)x, tid, NTHR, &detsh);

  // =========================== FC group ===================================
  if (wg >= NSCAN) {
    const int fcw = wg - NSCAN;        // 0..63
    const unsigned* fpoll = (wave == 0 && lane < WPG)
        ? flagp(flags, 3, lane, (fcw < 32) ? 2 : 3) : nullptr;
    const int sb  = tid / 24;          // 0..15 (batch row)
    const int seg = tid % 24;          // 0..23 (32-elem segment)
    const int sx  = sb & 7;
    const int ar  = lane & 15;
    const int arx = ar & 7;

    for (int i = 0; i < 16; i++) {
      const int t = fcw + 64 * i;
      // ---- wait: all GH2 WGs completed tick t+4 (=> y2[t] stored+acked) --
      if (wave == 0) {
        const int tgt = t + 5;
        for (;;) {
          int v = fpoll ? (int)agent_ld32(fpoll) : 0x7FFFFFFF;
          if (__ballot(v < tgt) == 0ull) break;
          __builtin_amdgcn_s_sleep(8);
        }
      }
      __syncthreads();

      // ---- stage y2[:, t, :] (16 x 768 bf16) into LDS, swizzled ---------
      {
        const ushort* src = y2 + ((size_t)sb * TLEN + t) * H + seg * 32;
        u32x4 r4[4];
        ld64B_agent(src, r4);
        #pragma unroll
        for (int j = 0; j < 4; j++)
          *(u32x4*)&h_lds[sb * H + (((seg * 4 + j) ^ sx) * 8)] = r4[j];
      }
      __syncthreads();

      // ---- MFMA: out[:, t, n0..n0+128) per wave (waves 0..3) ------------
      if (wave < 4) {
        const int n0 = wave * 128;
        const ushort* abase = &h_lds[ar * H];
        f32x4 acc[8];
        #pragma unroll
        for (int nt = 0; nt < 8; nt++) acc[nt] = (f32x4){0.f, 0.f, 0.f, 0.f};
        for (int kk = 0; kk < 12; kk++) {
          short8 a0 = *(const short8*)&abase[((quad + 4 * kk) ^ arx) * 8];
          short8 a1 = *(const short8*)&abase[((quad + 4 * (kk + 12)) ^ arx) * 8];
          #pragma unroll
          for (int nt = 0; nt < 8; nt++) {
            const size_t bb = (size_t)(n0 + nt * 16 + ar) * H + quad * 8;
            short8 b0 = loadA8(w_fc, isbf, bb + kk * 32);
            short8 b1 = loadA8(w_fc, isbf, bb + (kk + 12) * 32);
            acc[nt] = __builtin_amdgcn_mfma_f32_16x16x32_bf16(a0, b0, acc[nt], 0, 0, 0);
            acc[nt] = __builtin_amdgcn_mfma_f32_16x16x32_bf16(a1, b1, acc[nt], 0, 0, 0);
          }
        }
        #pragma unroll
        for (int nt = 0; nt < 8; nt++) {
          #pragma unroll
          for (int i2 = 0; i2 < 4; i2++) {
            const int b = quad * 4 + i2;
            const int n = n0 + nt * 16 + ar;
            float v = acc[nt][i2] + loadS(b_fc, isbf, n);
            float g = 0.5f * v * (1.0f + erff(v * 0.70710678118654752f));
            if (isbf) ((ushort*)out)[((size_t)b * TLEN + t) * DOUT + n] = f2b(g);
            else      ((float*)out)[((size_t)b * TLEN + t) * DOUT + n] = g;
          }
        }
      }
      __syncthreads();                 // LDS reuse guard before next t
    }
    return;
  }

  // =========================== scan groups ================================
  const int grp  = wg / WPG;           // 0..3
  const int wgi  = wg % WPG;           // 0..23 -> gate columns [wgi*32, +32)
  const bool isL = (grp == 1 || grp == 3);

  for (int i = tid; i < BATCH * SLICE; i += NTHR) hold[i] = 0.0f;

  if (isL) {
    size_t boff = (grp == 3) ? (size_t)G3 : 0;
    for (int gf = tid; gf < 96; gf += NTHR) {
      size_t gidx = boff + (size_t)(gf >> 5) * H + wgi * SLICE + (gf & 31);
      bih_s[gf] = loadS(b_ih, isbf, gidx);
      bhh_s[gf] = loadS(b_hh, isbf, gidx);
    }
  }

  // ---- per-lane poll pointer + threshold offset (wave 0 only) ----
  const unsigned* pollp = nullptr;
  int polloff = 0;
  if (wave == 0) {
    if (grp == 0) {
      if (lane == 0) { pollp = flagp(flags, 1, wgi, 2); polloff = -6; }
    } else if (grp == 1) {
      if      (lane == 0)  { pollp = flagp(flags, 0, wgi, 0);       polloff = 0;  }
      else if (lane <= 24) { pollp = flagp(flags, 1, lane - 1, 0);  polloff = 0;  }
      else if (lane <= 48) { pollp = flagp(flags, 2, lane - 25, 0); polloff = -6; }
    } else if (grp == 2) {
      if      (lane < 24)  { pollp = flagp(flags, 1, lane, 1);      polloff = 0;  }
      else if (lane == 24) { pollp = flagp(flags, 3, wgi, 1);       polloff = -5; }
    } else {
      if      (lane == 0)  { pollp = flagp(flags, 2, wgi, 1);       polloff = -1; }
      else if (lane <= 24) { pollp = flagp(flags, 3, lane - 1, 0);  polloff = 0;  }
    }
  }

  // ---- load this wave's B-fragments (16 gate rows x K=768) into registers --
  const void* Wmat = (grp == 0 || grp == 2) ? w_ih : w_hh;
  const size_t woff = (grp >= 2) ? (size_t)G3 * H : 0;
  const int gate   = wave >> 1;                       // 0=r,1=z,2=n
  const int gfbase = gate * SLICE + (wave & 1) * 16;  // within-wg flat gate base
  const int nrow   = gate * H + wgi * SLICE + (wave & 1) * 16 + (lane & 15);
  const size_t wbase = woff + (size_t)nrow * H + quad * 8;

  short8 bfrag[24];
  #pragma unroll
  for (int kk = 0; kk < 24; kk++)
    bfrag[kk] = loadW8(Wmat, isbf, wbase + kk * 32);

  // staging decomposition: thread -> (row b, 32-elem segment = 4 x 16B units)
  const int sb  = tid / 24;            // 0..15
  const int seg = tid % 24;            // 0..23
  const int sx  = sb & 7;              // staging swizzle key

  // combine decomposition: 256 threads, pairs of columns
  const int pb = tid >> 4;             // batch
  const int pj = (tid & 15) * 2;       // column pair
  const bool pact = isL && (tid < BATCH * SLICE / 2);

  const int lag = (grp == 1) ? 1 : ((grp == 2) ? 2 : ((grp == 3) ? 4 : 0));

  __syncthreads();

  for (int t = 0; t < TLEN + 4; t++) {
    const int tau = t - lag;
    const bool active = (tau >= 0) && (tau < TLEN);

    if (active) {
      // ---- dependency wait ----
      if (wave == 0) {
        for (;;) {
          int v = pollp ? (int)agent_ld32(pollp) : 0x7FFFFFFF;
          if (__ballot(v < t + polloff) == 0ull) break;
          __builtin_amdgcn_s_sleep(1);
        }
      }
      __syncthreads();

      // ---- early-issue combine-phase gx loads (producer >=1 tick ahead) --
      unsigned long long gr01 = 0, gz01 = 0, gn01 = 0;
      if (pact) {
        const float* gxr = ((grp == 1) ? gxbuf1 : gxbuf2)
            + ((size_t)((tau & 7) * WPG + wgi) * BATCH + pb) * 96;
        gr01 = agent_ld64(gxr + pj);
        gz01 = agent_ld64(gxr + 32 + pj);
        gn01 = agent_ld64(gxr + 64 + pj);
      }

      // ---- stage A tile (16 x 768) into LDS (XOR-swizzled units) ----
      if (grp == 0) {
        const size_t srcbase = ((size_t)sb * TLEN + tau) * H + seg * 32;
        #pragma unroll
        for (int i = 0; i < 4; i++) {
          short8 v = loadA8(x, isbf, srcbase + i * 8);
          *(short8*)&h_lds[sb * H + (((seg * 4 + i) ^ sx) * 8)] = v;
        }
      } else {
        const int hstep = (grp == 3) ? (t - 5) : (t - 2);
        u32x4 r4[4];
        if (hstep >= 0) {
          const ushort* src = (grp == 3)
              ? y2 + ((size_t)sb * TLEN + hstep) * H + seg * 32
              : h1buf + (size_t)(hstep & 7) * (BATCH * H) + (size_t)sb * H + seg * 32;
          ld64B_agent(src, r4);
        } else {
          r4[0] = (u32x4){0u, 0u, 0u, 0u};
          r4[1] = r4[0]; r4[2] = r4[0]; r4[3] = r4[0];
        }
        #pragma unroll
        for (int j = 0; j < 4; j++)
          *(u32x4*)&h_lds[sb * H + (((seg * 4 + j) ^ sx) * 8)] = r4[j];
      }
      __syncthreads();

      // ---- MFMA: A from LDS (swizzled read), B from registers ----
      const int ar  = lane & 15;
      const int arx = ar & 7;
      const ushort* abase = &h_lds[ar * H];
      f32x4 acc0 = {0.f, 0.f, 0.f, 0.f}, acc1 = {0.f, 0.f, 0.f, 0.f};
      #pragma unroll
      for (int kk = 0; kk < 12; kk++) {
        short8 a0 = *(const short8*)&abase[((quad + 4 * kk) ^ arx) * 8];
        short8 a1 = *(const short8*)&abase[((quad + 4 * (kk + 12)) ^ arx) * 8];
        acc0 = __builtin_amdgcn_mfma_f32_16x16x32_bf16(a0, bfrag[kk],      acc0, 0, 0, 0);
        acc1 = __builtin_amdgcn_mfma_f32_16x16x32_bf16(a1, bfrag[kk + 12], acc1, 0, 0, 0);
      }
      f32x4 acc = acc0 + acc1;

      // ---- stage C tile to LDS ----
      #pragma unroll
      for (int i = 0; i < 4; i++)
        ghs[(gfbase + ar) * 17 + quad * 4 + i] = acc[i];
      __syncthreads();

      if (!isL) {
        // pack gx slice [16][96] f32 -> coalesced 8B agent stores
        float* gxout = ((grp == 0) ? gxbuf1 : gxbuf2)
            + ((size_t)(tau & 7) * WPG + wgi) * BATCH * 96;
        const int m  = tid / 24;
        const int c4 = (tid % 24) * 4;
        union { unsigned long long q; float f[2]; } p0, p1;
        p0.f[0] = ghs[(c4 + 0) * 17 + m];
        p0.f[1] = ghs[(c4 + 1) * 17 + m];
        p1.f[0] = ghs[(c4 + 2) * 17 + m];
        p1.f[1] = ghs[(c4 + 3) * 17 + m];
        agent_st64(gxout + (size_t)m * 96 + c4,     p0.q);
        agent_st64(gxout + (size_t)m * 96 + c4 + 2, p1.q);
      } else if (pact) {
        union { unsigned long long q; float f[2]; } ur, uz, un;
        ur.q = gr01; uz.q = gz01; un.q = gn01;
        unsigned hpack = 0;
        #pragma unroll
        for (int s = 0; s < 2; s++) {
          const int j = pj + s;
          float rpre = ur.f[s] + bih_s[j]      + ghs[j * 17 + pb]        + bhh_s[j];
          float zpre = uz.f[s] + bih_s[32 + j] + ghs[(32 + j) * 17 + pb] + bhh_s[32 + j];
          float hn   = ghs[(64 + j) * 17 + pb] + bhh_s[64 + j];
          float r = 1.0f / (1.0f + expf(-rpre));
          float z = 1.0f / (1.0f + expf(-zpre));
          float n = tanhf(un.f[s] + bih_s[64 + j] + r * hn);
          float hnew = (1.0f - z) * n + z * hold[pb * SLICE + j];
          hold[pb * SLICE + j] = hnew;
          hpack |= ((unsigned)f2b(hnew)) << (16 * s);
        }
        if (grp == 1)
          agent_st32(h1buf + (size_t)(tau & 7) * (BATCH * H)
                           + (size_t)pb * H + wgi * SLICE + pj, hpack);
        else
          agent_st32(&y2[((size_t)pb * TLEN + tau) * H + wgi * SLICE + pj], hpack);
      }
    }

    // ---- post completion flag (after vmcnt drain) ----
    __syncthreads();                       // drains vmcnt: comms stores visible
    if (tid < 4) agent_st32(flagp(flags, grp, wgi, tid), (unsigned)(t + 1));
  }
}

extern "C" void kernel_launch(void* const* d_in, const int* in_sizes, int n_in,
                              void* d_out, int out_size, void* d_ws, size_t ws_size,
                              hipStream_t stream) {
  const void* x    = d_in[0];
  const void* w_ih = d_in[1];
  const void* w_hh = d_in[2];
  const void* b_ih = d_in[3];
  const void* b_hh = d_in[4];
  const void* w_fc = d_in[5];
  const void* b_fc = d_in[6];

  char* ws = (char*)d_ws;
  // layout: [0,49152) flags[4][24][4][32] |
  //         [53248,249856) h1 (8-deep) | [249856,1429504) gx1 (8-deep) |
  //         [1429504,2609152) gx2 (8-deep) | [2609152,27774976) y2 (=h2 hist)
  unsigned int* flags = (unsigned int*)(ws);
  ushort* h1buf  = (ushort*)(ws + 53248);
  float*  gxbuf1 = (float*)(ws + 249856);
  float*  gxbuf2 = (float*)(ws + 1429504);
  ushort* y2     = (ushort*)(ws + 2609152);

  hipMemsetAsync(ws, 0, 49152, stream);  // flags only (data is flag-gated)
  scan_kernel<<<dim3(NWG), dim3(NTHR), 0, stream>>>(
      x, w_ih, w_hh, b_ih, b_hh, w_fc, b_fc, flags,
      h1buf, gxbuf1, gxbuf2, y2, d_out);
}